// Round 8
// baseline (164.637 us; speedup 1.0000x reference)
//
#include <hip/hip_runtime.h>
#include <hip/hip_bf16.h>

#define BATCH 16
#define TLEN 2048
#define CDIM 1024
#define HDIM 128

typedef __attribute__((ext_vector_type(8))) short bf16x8;
typedef __attribute__((ext_vector_type(4))) float f32x4;
typedef __attribute__((ext_vector_type(16))) float f32x16;
typedef __attribute__((ext_vector_type(4))) unsigned short u16x4;
typedef __attribute__((ext_vector_type(8))) unsigned short u16x8;

static __device__ __forceinline__ unsigned short f2bf(float f) {
    __hip_bfloat16 h = __float2bfloat16(f);
    return *(unsigned short*)&h;
}
static __device__ __forceinline__ unsigned pkbf(float a, float b) {
    return (unsigned)f2bf(a) | ((unsigned)f2bf(b) << 16);
}
// partials per (b,qc) prefix:  sum_{j<qc} (j/2 + 1)
static __device__ __forceinline__ int part_offs(int qc) {
    return qc + ((qc * qc - 2 * qc + (qc & 1)) >> 2);
}

typedef const __attribute__((address_space(1))) unsigned int* gas_t;
typedef __attribute__((address_space(3))) unsigned int* las_t;
static __device__ __forceinline__ void gl_lds16(const void* g, void* l) {
    __builtin_amdgcn_global_load_lds((gas_t)g, (las_t)l, 16, 0, 0);
}

// ---------------------------------------------------------------------------
// Prep 1: x (fp32) -> xb (bf16), vectorized grid-stride.
// ---------------------------------------------------------------------------
__global__ __launch_bounds__(256) void x2bf(
    const float* __restrict__ x, unsigned short* __restrict__ xb)
{
    const size_t n8 = (size_t)BATCH * TLEN * CDIM / 8;
    const size_t stride = (size_t)gridDim.x * 256;
    for (size_t i = (size_t)blockIdx.x * 256 + threadIdx.x; i < n8; i += stride) {
        const float4 f0 = ((const float4*)x)[2 * i];
        const float4 f1 = ((const float4*)x)[2 * i + 1];
        u16x8 o;
        o[0] = f2bf(f0.x); o[1] = f2bf(f0.y); o[2] = f2bf(f0.z); o[3] = f2bf(f0.w);
        o[4] = f2bf(f1.x); o[5] = f2bf(f1.y); o[6] = f2bf(f1.z); o[7] = f2bf(f1.w);
        *(u16x8*)(xb + i * 8) = o;
    }
}

// ---------------------------------------------------------------------------
// Prep 2: pack Wq|Wk|Wv into transposed bf16  wtb[(which*128+n)*1024 + k].
// ---------------------------------------------------------------------------
__global__ __launch_bounds__(256) void pack_w(
    const float* __restrict__ Wq, const float* __restrict__ Wk,
    const float* __restrict__ Wv, unsigned short* __restrict__ wtb)
{
    const int which = blockIdx.y;
    const float* W = (which == 0) ? Wq : (which == 1) ? Wk : Wv;
    const int n = blockIdx.x >> 2;
    const int k = (blockIdx.x & 3) * 256 + threadIdx.x;
    wtb[((size_t)which * 128 + n) * 1024 + k] = f2bf(W[(size_t)k * 128 + n]);
}

// ---------------------------------------------------------------------------
// Kernel 1: QKV projection, bf16 MFMA, m97 structure:
// 128x128 tile, BK=64, 4 waves, LINEAR LDS + global_load_lds width-16,
// 2 barriers per K-step.  XCD swizzle: the 3 nt-blocks of one x-tile run on
// the same XCD (L2 reuse of xb).
// ---------------------------------------------------------------------------
__global__ __launch_bounds__(256) void qkv_mfma(
    const unsigned short* __restrict__ xb, const unsigned short* __restrict__ wtb,
    unsigned short* __restrict__ qb, unsigned short* __restrict__ kb,
    unsigned short* __restrict__ vtb)
{
    __shared__ unsigned short As[128 * 64];   // [m][k] linear
    __shared__ unsigned short Bs[128 * 64];   // [n][k] linear

    const int bid = blockIdx.x;           // 0..767
    const int xcd = bid & 7, s = bid >> 3;
    const int m0 = (xcd * 32 + s / 3) * 128;
    const int nt = s % 3;

    const int tid  = threadIdx.x;
    const int lane = tid & 63, wid = tid >> 6;
    const int wm = wid >> 1, wn = wid & 1;
    const int c = lane & 15, g = lane >> 4;
    const unsigned short* Wp = wtb + (size_t)nt * 128 * 1024;

    // staging geometry: 16 segments of 1024B per tile; wave w owns segs 4w..4w+3.
    // lane l writes LDS bytes [seg*1024 + 16l, +16) = row seg*8 + (l>>3),
    // k-shorts (l&7)*8.. -> per-lane global src must match that order.
    const int lrow = lane >> 3;
    const int lcol = (lane & 7) * 8;

    f32x4 acc[4][4];
#pragma unroll
    for (int i = 0; i < 4; ++i)
#pragma unroll
        for (int j = 0; j < 4; ++j) acc[i][j] = (f32x4){0.f, 0.f, 0.f, 0.f};

#define STAGE(k0_)                                                            \
    {                                                                         \
        _Pragma("unroll")                                                     \
        for (int i = 0; i < 4; ++i) {                                         \
            const int seg = wid * 4 + i;                                      \
            const unsigned short* ga = xb +                                   \
                (size_t)(m0 + seg * 8 + lrow) * CDIM + (k0_) + lcol;          \
            const unsigned short* gb = Wp +                                   \
                (size_t)(seg * 8 + lrow) * CDIM + (k0_) + lcol;               \
            gl_lds16(ga, (char*)As + seg * 1024);                             \
            gl_lds16(gb, (char*)Bs + seg * 1024);                             \
        }                                                                     \
    }

    STAGE(0);

#pragma unroll 1
    for (int kt = 0; kt < 16; ++kt) {
        __syncthreads();   // compiler drains vmcnt(0) before the barrier

#pragma unroll
        for (int ks = 0; ks < 2; ++ks) {
            bf16x8 af[4], bf[4];
#pragma unroll
            for (int mf = 0; mf < 4; ++mf) {
                const int row = wm * 64 + mf * 16 + c;
                af[mf] = *(const bf16x8*)((char*)As + row * 128 + ks * 64 + g * 16);
            }
#pragma unroll
            for (int nf = 0; nf < 4; ++nf) {
                const int row = wn * 64 + nf * 16 + c;
                bf[nf] = *(const bf16x8*)((char*)Bs + row * 128 + ks * 64 + g * 16);
            }
#pragma unroll
            for (int mf = 0; mf < 4; ++mf)
#pragma unroll
                for (int nf = 0; nf < 4; ++nf)
                    acc[mf][nf] = __builtin_amdgcn_mfma_f32_16x16x32_bf16(
                        af[mf], bf[nf], acc[mf][nf], 0, 0, 0);
        }

        if (kt < 15) {
            __syncthreads();           // all waves done reading As/Bs
            STAGE((kt + 1) * 64);      // async loads fly across next barrier
        }
    }

    const int mb = m0 + wm * 64, nb = wn * 64;
    if (nt == 0) {
#pragma unroll
        for (int mf = 0; mf < 4; ++mf)
#pragma unroll
            for (int nf = 0; nf < 4; ++nf)
#pragma unroll
                for (int r = 0; r < 4; ++r) {
                    const int m = mb + mf * 16 + g * 4 + r;
                    const int n = nb + nf * 16 + c;
                    qb[(size_t)m * HDIM + n] = f2bf(acc[mf][nf][r] * 0.03125f);
                }
    } else if (nt == 1) {
#pragma unroll
        for (int mf = 0; mf < 4; ++mf)
#pragma unroll
            for (int nf = 0; nf < 4; ++nf)
#pragma unroll
                for (int r = 0; r < 4; ++r) {
                    const int m = mb + mf * 16 + g * 4 + r;
                    const int n = nb + nf * 16 + c;
                    kb[(size_t)m * HDIM + n] = f2bf(acc[mf][nf][r]);
                }
    } else {
#pragma unroll
        for (int mf = 0; mf < 4; ++mf)
#pragma unroll
            for (int nf = 0; nf < 4; ++nf) {
                const int m = mb + mf * 16 + g * 4;
                const int b = m >> 11, t = m & (TLEN - 1);
                const int n = nb + nf * 16 + c;
                u16x4 o;
                o[0] = f2bf(acc[mf][nf][0]); o[1] = f2bf(acc[mf][nf][1]);
                o[2] = f2bf(acc[mf][nf][2]); o[3] = f2bf(acc[mf][nf][3]);
                *(u16x4*)(vtb + ((size_t)b * HDIM + n) * TLEN + t) = o;
            }
    }
#undef STAGE
}

// ---------------------------------------------------------------------------
// Kernel 2a: flash-attention partials, 32x32 swapped-operand structure
// (unchanged from round 7 except T5 setprio around MFMA clusters).
// ---------------------------------------------------------------------------
__global__ __launch_bounds__(256, 2) void attn_partial(
    const short* __restrict__ qb, const short* __restrict__ kb,
    const short* __restrict__ vtb,
    unsigned short* __restrict__ Opart, float* __restrict__ mpart,
    float* __restrict__ lpart)
{
    const int kc = blockIdx.x;          // 0..7   (256-key chunk)
    const int qc = blockIdx.y;          // 0..15  (128-row chunk)
    const int b  = blockIdx.z;
    if (kc > (qc >> 1)) return;
    const int kv_base = kc * 256;
    const int qrel = qc * 128 - kv_base;
    int NT = ((qrel + 127) >> 6) + 1; if (NT > 4) NT = 4;

    __shared__ unsigned short Ks[2][64 * 128];   // 32KB [buf][key][h] swizzled
    __shared__ unsigned short Vs[2][128 * 64];   // 32KB [buf][h][key] swizzled

    const int tid  = threadIdx.x;
    const int wid  = tid >> 6;
    const int lane = tid & 63;
    const int c5 = lane & 31, hi = lane >> 5;
    const int q0w = qc * 128 + wid * 32;
    const int qg  = q0w + c5;
    const int pidx = b * 72 + part_offs(qc) + kc;

    const short* Kb  = kb  + (size_t)b * TLEN * HDIM;
    const short* Vtb = vtb + (size_t)b * HDIM * TLEN;

    bf16x8 qf[8];
#pragma unroll
    for (int ks = 0; ks < 8; ++ks)
        qf[ks] = *(const bf16x8*)(qb + ((size_t)b * TLEN + qg) * HDIM + ks * 16 + hi * 8);

    bf16x8 kst[4], vst[4];

#define GLOAD(kv0_)                                                          \
    {                                                                        \
        _Pragma("unroll")                                                    \
        for (int it = 0; it < 4; ++it) {                                     \
            const int o = tid * 16 + it * 4096;                              \
            const int kr = o >> 8, kcb = o & 0xF0;                           \
            kst[it] = *(const bf16x8*)((const char*)Kb +                     \
                        (size_t)((kv0_) + kr) * 256 + kcb);                  \
            const int vr = o >> 7, vcb = o & 0x70;                           \
            vst[it] = *(const bf16x8*)((const char*)Vtb +                    \
                        (size_t)vr * (TLEN * 2) + (size_t)(kv0_) * 2 + vcb); \
        }                                                                    \
    }
#define SSTORE(bi_)                                                          \
    {                                                                        \
        _Pragma("unroll")                                                    \
        for (int it = 0; it < 4; ++it) {                                     \
            const int o = tid * 16 + it * 4096;                              \
            const int kr = o >> 8, kcb = o & 0xF0;                           \
            *(bf16x8*)((char*)Ks[bi_] + kr * 256 + (kcb ^ ((kr & 7) << 4))) = kst[it]; \
            const int vr = o >> 7, vcb = o & 0x70;                           \
            *(bf16x8*)((char*)Vs[bi_] + vr * 128 + (vcb ^ ((vr & 7) << 4))) = vst[it]; \
        }                                                                    \
    }

    GLOAD(kv_base);
    SSTORE(0);
    __syncthreads();

    f32x16 oacc[4];
#pragma unroll
    for (int i = 0; i < 4; ++i)
#pragma unroll
        for (int r = 0; r < 16; ++r) oacc[i][r] = 0.f;
    float m_r = -1e30f;
    float l_r = 0.f;

#pragma unroll 1
    for (int t = 0; t < NT; ++t) {
        const int bi = t & 1;
        if (t + 1 < NT) GLOAD(kv_base + 64 * (t + 1));

        const int kv0 = kv_base + 64 * t;
        if (kv0 <= q0w + 31) {
            // ---- QK^T: S^T[key][q], two 32-key blocks ----
            f32x16 s0, s1;
#pragma unroll
            for (int r = 0; r < 16; ++r) { s0[r] = 0.f; s1[r] = 0.f; }
            __builtin_amdgcn_s_setprio(1);
#pragma unroll
            for (int ks = 0; ks < 8; ++ks) {
                const int col = ks * 32 + hi * 16;
                const int off0 = c5 * 256 + (col ^ ((c5 & 7) << 4));
                const int off1 = (32 + c5) * 256 + (col ^ ((c5 & 7) << 4));
                bf16x8 a0 = *(const bf16x8*)((char*)Ks[bi] + off0);
                bf16x8 a1 = *(const bf16x8*)((char*)Ks[bi] + off1);
                s0 = __builtin_amdgcn_mfma_f32_32x32x16_bf16(a0, qf[ks], s0, 0, 0, 0);
                s1 = __builtin_amdgcn_mfma_f32_32x32x16_bf16(a1, qf[ks], s1, 0, 0, 0);
            }
            __builtin_amdgcn_s_setprio(0);

            // ---- causal mask (only near diagonal) ----
            if (kv0 + 63 > q0w) {
#pragma unroll
                for (int r = 0; r < 16; ++r) {
                    const int key0 = kv0 + (r & 3) + 8 * (r >> 2) + 4 * hi;
                    if (key0 > qg)      s0[r] = -INFINITY;
                    if (key0 + 32 > qg) s1[r] = -INFINITY;
                }
            }

            // ---- in-register online softmax ----
            float t8[8];
#pragma unroll
            for (int i = 0; i < 8; ++i)
                t8[i] = fmaxf(fmaxf(s0[2*i], s0[2*i+1]), fmaxf(s1[2*i], s1[2*i+1]));
            float smax = fmaxf(fmaxf(fmaxf(t8[0], t8[1]), fmaxf(t8[2], t8[3])),
                               fmaxf(fmaxf(t8[4], t8[5]), fmaxf(t8[6], t8[7])));
            smax = fmaxf(smax, __shfl_xor(smax, 32));

            const bool defer = __all(smax - m_r <= 8.0f);   // T13
            const float mnew = defer ? m_r : fmaxf(m_r, smax);
            if (!defer) {
                const float alpha = __expf(m_r - mnew);
                l_r *= alpha;
#pragma unroll
                for (int hb = 0; hb < 4; ++hb) oacc[hb] = oacc[hb] * alpha;
            }
            m_r = mnew;

#pragma unroll
            for (int r = 0; r < 16; ++r) {
                s0[r] = __expf(s0[r] - mnew);
                s1[r] = __expf(s1[r] - mnew);
            }
            float a8[8];
#pragma unroll
            for (int i = 0; i < 8; ++i)
                a8[i] = (s0[2*i] + s0[2*i+1]) + (s1[2*i] + s1[2*i+1]);
            float psum = ((a8[0] + a8[1]) + (a8[2] + a8[3])) +
                         ((a8[4] + a8[5]) + (a8[6] + a8[7]));
            psum += __shfl_xor(psum, 32);
            l_r += psum;

            // ---- pack P -> B-operand frags (P^T[k][q]) ----
            bf16x8 pa[4];
#pragma unroll
            for (int kb2 = 0; kb2 < 2; ++kb2) {
#pragma unroll
                for (int par = 0; par < 2; ++par) {
                    const int e = par * 8;
                    float v0, v1, v2, v3, v4, v5, v6, v7;
                    if (kb2 == 0) {
                        v0=s0[e+0]; v1=s0[e+1]; v2=s0[e+2]; v3=s0[e+3];
                        v4=s0[e+4]; v5=s0[e+5]; v6=s0[e+6]; v7=s0[e+7];
                    } else {
                        v0=s1[e+0]; v1=s1[e+1]; v2=s1[e+2]; v3=s1[e+3];
                        v4=s1[e+4]; v5=s1[e+5]; v6=s1[e+6]; v7=s1[e+7];
                    }
                    const unsigned w0 = pkbf(v0, v1), w1 = pkbf(v2, v3);
                    const unsigned w2 = pkbf(v4, v5), w3 = pkbf(v6, v7);
                    const unsigned X0 = hi ? w0 : w2;
                    const unsigned X1 = hi ? w1 : w3;
                    const unsigned R0 = (unsigned)__shfl_xor((int)X0, 32);
                    const unsigned R1 = (unsigned)__shfl_xor((int)X1, 32);
                    union { unsigned w[4]; bf16x8 v; } uu;
                    uu.w[0] = hi ? R0 : w0;  uu.w[1] = hi ? R1 : w1;
                    uu.w[2] = hi ? w2 : R0;  uu.w[3] = hi ? w3 : R1;
                    pa[kb2 * 2 + par] = uu.v;
                }
            }

            // ---- PV: O[h][q] += V^T . P^T ----
            __builtin_amdgcn_s_setprio(1);
#pragma unroll
            for (int hb = 0; hb < 4; ++hb) {
                const int row = hb * 32 + c5;
#pragma unroll
                for (int ks = 0; ks < 4; ++ks) {
                    const int off = row * 128 + ((ks * 32 + hi * 16) ^ ((row & 7) << 4));
                    bf16x8 va = *(const bf16x8*)((char*)Vs[bi] + off);
                    oacc[hb] = __builtin_amdgcn_mfma_f32_32x32x16_bf16(va, pa[ks], oacc[hb], 0, 0, 0);
                }
            }
            __builtin_amdgcn_s_setprio(0);
        }

        if (t + 1 < NT) {
            SSTORE(bi ^ 1);
            __syncthreads();
        }
    }

    // ---- epilogue: transpose O via LDS, store partials bf16 ----
    __syncthreads();
    char* sl = (char*)Ks + wid * 8192;
#pragma unroll
    for (int hb = 0; hb < 4; ++hb)
#pragma unroll
        for (int rq = 0; rq < 4; ++rq) {
            u16x4 o4;
            o4[0] = f2bf(oacc[hb][rq * 4 + 0]);
            o4[1] = f2bf(oacc[hb][rq * 4 + 1]);
            o4[2] = f2bf(oacc[hb][rq * 4 + 2]);
            o4[3] = f2bf(oacc[hb][rq * 4 + 3]);
            const int off = c5 * 256 + ((hb * 64 + rq * 16 + hi * 8) ^ ((c5 & 7) << 4));
            *(u16x4*)(sl + off) = o4;
        }
    asm volatile("s_waitcnt lgkmcnt(0)" ::: "memory");
    __builtin_amdgcn_sched_barrier(0);

    const int qr = lane >> 1, hf = lane & 1;
    unsigned short* Og = Opart + (size_t)pidx * 128 * 128 +
                         (size_t)(wid * 32 + qr) * 128 + hf * 64;
#pragma unroll
    for (int i = 0; i < 8; ++i) {
        const int off = qr * 256 + ((hf * 128 + i * 16) ^ ((qr & 7) << 4));
        *(u16x8*)(Og + i * 8) = *(const u16x8*)(sl + off);
    }
    if (hi == 0) {
        mpart[(size_t)pidx * 128 + wid * 32 + c5] = m_r;
        lpart[(size_t)pidx * 128 + wid * 32 + c5] = l_r;
    }
#undef GLOAD
#undef SSTORE
}

// ---------------------------------------------------------------------------
// Kernel 2b: combine partials (unchanged).
// ---------------------------------------------------------------------------
__global__ __launch_bounds__(256) void attn_combine(
    const unsigned short* __restrict__ Opart, const float* __restrict__ mpart,
    const float* __restrict__ lpart, float* __restrict__ out)
{
    const int qc = blockIdx.x;
    const int b  = blockIdx.y;
    const int n  = (qc >> 1) + 1;
    const int base = b * 72 + part_offs(qc);
    const int t   = threadIdx.x;
    const int row = t >> 1;
    const int d0  = (t & 1) * 64;

    float M = -INFINITY;
    for (int p = 0; p < n; ++p)
        M = fmaxf(M, mpart[(size_t)(base + p) * 128 + row]);
    float L = 0.f;
    for (int p = 0; p < n; ++p)
        L += __expf(mpart[(size_t)(base + p) * 128 + row] - M) *
             lpart[(size_t)(base + p) * 128 + row];

    float acc[64];
#pragma unroll
    for (int i = 0; i < 64; ++i) acc[i] = 0.f;

    for (int p = 0; p < n; ++p) {
        const float w = __expf(mpart[(size_t)(base + p) * 128 + row] - M);
        const bf16x8* src = (const bf16x8*)(Opart +
            ((size_t)(base + p) * 128 + row) * 128 + d0);
#pragma unroll
        for (int j = 0; j < 8; ++j) {
            bf16x8 v = src[j];
#pragma unroll
            for (int e = 0; e < 8; ++e) {
                union { unsigned u; float f; } x;
                x.u = ((unsigned)(unsigned short)v[e]) << 16;
                acc[j * 8 + e] += w * x.f;
            }
        }
    }

    const float invL = 1.f / L;
    float4* dst = (float4*)(out + ((size_t)(b * TLEN + qc * 128 + row)) * 128 + d0);
#pragma unroll
    for (int i = 0; i < 16; ++i)
        dst[i] = make_float4(acc[4*i] * invL, acc[4*i+1] * invL,
                             acc[4*i+2] * invL, acc[4*i+3] * invL);
}

extern "C" void kernel_launch(void* const* d_in, const int* in_sizes, int n_in,
                              void* d_out, int out_size, void* d_ws, size_t ws_size,
                              hipStream_t stream)
{
    const float* x  = (const float*)d_in[0];
    const float* Wq = (const float*)d_in[1];
    const float* Wk = (const float*)d_in[2];
    const float* Wv = (const float*)d_in[3];
    float* outp = (float*)d_out;

    const size_t per = (size_t)BATCH * TLEN * HDIM;      // 4,194,304
    unsigned short* qb  = (unsigned short*)d_ws;
    unsigned short* kb  = qb + per;
    unsigned short* vtb = kb + per;
    unsigned short* wtb = vtb + per;                     // 384*1024 bf16
    unsigned short* xbuf = wtb + 384 * 1024;             // 33.55M bf16 (64MB)
    // Opart/mpart/lpart ALIAS xbuf: xb is fully consumed by qkv_mfma before
    // attn_partial writes Opart (same stream, sequential kernels).
    unsigned short* Opart = xbuf;                        // 1152*128*128 bf16
    float* mpart = (float*)(Opart + (size_t)1152 * 128 * 128);
    float* lpart = mpart + (size_t)1152 * 128;

    x2bf<<<2048, 256, 0, stream>>>(x, xbuf);

    dim3 gw(512, 3);
    pack_w<<<gw, 256, 0, stream>>>(Wq, Wk, Wv, wtb);

    qkv_mfma<<<768, 256, 0, stream>>>(xbuf, wtb, qb, kb, vtb);

    dim3 g2(8, 16, BATCH);
    attn_partial<<<g2, 256, 0, stream>>>((const short*)qb, (const short*)kb,
                                         (const short*)vtb, Opart, mpart, lpart);

    dim3 g3(16, BATCH);
    attn_combine<<<g3, 256, 0, stream>>>(Opart, mpart, lpart, outp);
}

// Round 9
// 135.587 us; speedup vs baseline: 1.2143x; 1.2143x over previous
//
#include <hip/hip_runtime.h>
#include <hip/hip_bf16.h>

#define BATCH 16
#define TLEN 2048
#define CDIM 1024
#define HDIM 128

typedef __attribute__((ext_vector_type(8))) short bf16x8;
typedef __attribute__((ext_vector_type(4))) float f32x4;
typedef __attribute__((ext_vector_type(16))) float f32x16;
typedef __attribute__((ext_vector_type(4))) unsigned short u16x4;
typedef __attribute__((ext_vector_type(8))) unsigned short u16x8;

static __device__ __forceinline__ unsigned short f2bf(float f) {
    __hip_bfloat16 h = __float2bfloat16(f);
    return *(unsigned short*)&h;
}
static __device__ __forceinline__ unsigned pkbf(float a, float b) {
    return (unsigned)f2bf(a) | ((unsigned)f2bf(b) << 16);
}
// partials per (b,qc) prefix:  sum_{j<qc} (j/2 + 1)
static __device__ __forceinline__ int part_offs(int qc) {
    return qc + ((qc * qc - 2 * qc + (qc & 1)) >> 2);
}

typedef const __attribute__((address_space(1))) unsigned int* gas_t;
typedef __attribute__((address_space(3))) unsigned int* las_t;
static __device__ __forceinline__ void gl_lds16(const void* g, void* l) {
    __builtin_amdgcn_global_load_lds((gas_t)g, (las_t)l, 16, 0, 0);
}

// ---------------------------------------------------------------------------
// Prep: pack Wq|Wk|Wv into transposed bf16  wtb[(which*128+n)*1024 + k].
// ---------------------------------------------------------------------------
__global__ __launch_bounds__(256) void pack_w(
    const float* __restrict__ Wq, const float* __restrict__ Wk,
    const float* __restrict__ Wv, unsigned short* __restrict__ wtb)
{
    const int which = blockIdx.y;
    const float* W = (which == 0) ? Wq : (which == 1) ? Wk : Wv;
    const int n = blockIdx.x >> 2;
    const int k = (blockIdx.x & 3) * 256 + threadIdx.x;
    wtb[((size_t)which * 128 + n) * 1024 + k] = f2bf(W[(size_t)k * 128 + n]);
}

// ---------------------------------------------------------------------------
// Kernel 1: FUSED QKV projection.  C[64 x 384] per block, x read ONCE.
// BM=64, BN=384 (q|k|v), BK=32, 512 blocks (2/CU), 4 waves of 64x96.
// B (wtb, L2-hot) via global_load_lds w16, double-buffered, STAGE-first,
// ONE barrier per K-step (correct T3 shape).  A (x fp32, HBM) reg-staged:
// load -> (compute) -> cvt -> ds_write into next buffer -> barrier.
// ---------------------------------------------------------------------------
__global__ __launch_bounds__(256, 2) void qkv_fused(
    const float* __restrict__ x, const unsigned short* __restrict__ wtb,
    unsigned short* __restrict__ qb, unsigned short* __restrict__ kb,
    unsigned short* __restrict__ vtb)
{
    __shared__ unsigned short Abf[2][64 * 32];    // 2 x 4KB   [m][k]
    __shared__ unsigned short Bs[2][384 * 32];    // 2 x 24KB  [n][k]

    const int tid  = threadIdx.x;
    const int lane = tid & 63, wid = tid >> 6;    // 4 waves
    const int c = lane & 15, g = lane >> 4;
    const int m0 = blockIdx.x * 64;

    // A staging: thread -> row tid>>2 (0..63), k-chunk (tid&3)*8 (8 f32 = 32B)
    const int arow = tid >> 2;
    const int acol = (tid & 3) * 8;
    const float* xsrc = x + (size_t)(m0 + arow) * CDIM + acol;

    // B staging: wave wid owns segs wid*6..wid*6+5 (1024B each);
    // lane l -> row seg*16 + (l>>2), k-shorts (l&3)*8 (16B)
    const int brow = lane >> 2, bcol = (lane & 3) * 8;

    f32x4 acc[4][6];
#pragma unroll
    for (int i = 0; i < 4; ++i)
#pragma unroll
        for (int j = 0; j < 6; ++j) acc[i][j] = (f32x4){0.f, 0.f, 0.f, 0.f};

    float4 a0, a1;

#define GLA(k0_)                                                             \
    { a0 = *(const float4*)(xsrc + (k0_));                                   \
      a1 = *(const float4*)(xsrc + (k0_) + 4); }

#define CVTW(bi_)                                                            \
    { u16x8 t_;                                                              \
      t_[0]=f2bf(a0.x); t_[1]=f2bf(a0.y); t_[2]=f2bf(a0.z); t_[3]=f2bf(a0.w);\
      t_[4]=f2bf(a1.x); t_[5]=f2bf(a1.y); t_[6]=f2bf(a1.z); t_[7]=f2bf(a1.w);\
      *(u16x8*)((char*)Abf[bi_] + arow * 64 + acol * 2) = t_; }

#define STB(k0_, bi_)                                                        \
    { _Pragma("unroll")                                                      \
      for (int i_ = 0; i_ < 6; ++i_) {                                       \
          const int seg_ = wid * 6 + i_;                                     \
          const unsigned short* src_ = wtb +                                 \
              (size_t)(seg_ * 16 + brow) * 1024 + (k0_) + bcol;              \
          gl_lds16(src_, (char*)Bs[bi_] + seg_ * 1024);                      \
      } }

    // prologue: fill buffer 0
    GLA(0);
    STB(0, 0);
    CVTW(0);
    __syncthreads();

#pragma unroll 1
    for (int kt = 0; kt < 32; ++kt) {
        const int bi = kt & 1;
        if (kt < 31) {               // issue next tile BEFORE compute
            GLA((kt + 1) * 32);
            STB((kt + 1) * 32, bi ^ 1);
        }

        // ---- compute tile kt ----
        bf16x8 af[4], bf[6];
#pragma unroll
        for (int mf = 0; mf < 4; ++mf)
            af[mf] = *(const bf16x8*)((char*)Abf[bi] + (mf * 16 + c) * 64 + g * 16);
#pragma unroll
        for (int nf = 0; nf < 6; ++nf)
            bf[nf] = *(const bf16x8*)((char*)Bs[bi] + (wid * 96 + nf * 16 + c) * 64 + g * 16);
#pragma unroll
        for (int mf = 0; mf < 4; ++mf)
#pragma unroll
            for (int nf = 0; nf < 6; ++nf)
                acc[mf][nf] = __builtin_amdgcn_mfma_f32_16x16x32_bf16(
                    af[mf], bf[nf], acc[mf][nf], 0, 0, 0);

        if (kt < 31) CVTW(bi ^ 1);   // A for next tile (loads had full compute to land)
        __syncthreads();             // single barrier: drains B gl_lds + A ds_write
    }

    // ---- epilogue: per-fragment route to q (scaled) / k / v^T ----
#pragma unroll
    for (int mf = 0; mf < 4; ++mf) {
#pragma unroll
        for (int nf = 0; nf < 6; ++nf) {
            const int col0 = wid * 96 + nf * 16;
            const int nt = col0 >> 7;
            const int nc = (col0 & 127) + c;
            const int m = m0 + mf * 16 + g * 4;
            if (nt == 0) {
#pragma unroll
                for (int r = 0; r < 4; ++r)
                    qb[(size_t)(m + r) * HDIM + nc] = f2bf(acc[mf][nf][r] * 0.03125f);
            } else if (nt == 1) {
#pragma unroll
                for (int r = 0; r < 4; ++r)
                    kb[(size_t)(m + r) * HDIM + nc] = f2bf(acc[mf][nf][r]);
            } else {
                const int b = m >> 11, tl = m & (TLEN - 1);
                u16x4 o;
                o[0] = f2bf(acc[mf][nf][0]); o[1] = f2bf(acc[mf][nf][1]);
                o[2] = f2bf(acc[mf][nf][2]); o[3] = f2bf(acc[mf][nf][3]);
                *(u16x4*)(vtb + ((size_t)b * HDIM + nc) * TLEN + tl) = o;
            }
        }
    }
#undef GLA
#undef CVTW
#undef STB
}

// ---------------------------------------------------------------------------
// Kernel 2a: flash-attention partials, 32x32 swapped-operand structure
// (unchanged from round 8 — passed).
// ---------------------------------------------------------------------------
__global__ __launch_bounds__(256, 2) void attn_partial(
    const short* __restrict__ qb, const short* __restrict__ kb,
    const short* __restrict__ vtb,
    unsigned short* __restrict__ Opart, float* __restrict__ mpart,
    float* __restrict__ lpart)
{
    const int kc = blockIdx.x;
    const int qc = blockIdx.y;
    const int b  = blockIdx.z;
    if (kc > (qc >> 1)) return;
    const int kv_base = kc * 256;
    const int qrel = qc * 128 - kv_base;
    int NT = ((qrel + 127) >> 6) + 1; if (NT > 4) NT = 4;

    __shared__ unsigned short Ks[2][64 * 128];
    __shared__ unsigned short Vs[2][128 * 64];

    const int tid  = threadIdx.x;
    const int wid  = tid >> 6;
    const int lane = tid & 63;
    const int c5 = lane & 31, hi = lane >> 5;
    const int q0w = qc * 128 + wid * 32;
    const int qg  = q0w + c5;
    const int pidx = b * 72 + part_offs(qc) + kc;

    const short* Kb  = kb  + (size_t)b * TLEN * HDIM;
    const short* Vtb = vtb + (size_t)b * HDIM * TLEN;

    bf16x8 qf[8];
#pragma unroll
    for (int ks = 0; ks < 8; ++ks)
        qf[ks] = *(const bf16x8*)(qb + ((size_t)b * TLEN + qg) * HDIM + ks * 16 + hi * 8);

    bf16x8 kst[4], vst[4];

#define GLOAD(kv0_)                                                          \
    {                                                                        \
        _Pragma("unroll")                                                    \
        for (int it = 0; it < 4; ++it) {                                     \
            const int o = tid * 16 + it * 4096;                              \
            const int kr = o >> 8, kcb = o & 0xF0;                           \
            kst[it] = *(const bf16x8*)((const char*)Kb +                     \
                        (size_t)((kv0_) + kr) * 256 + kcb);                  \
            const int vr = o >> 7, vcb = o & 0x70;                           \
            vst[it] = *(const bf16x8*)((const char*)Vtb +                    \
                        (size_t)vr * (TLEN * 2) + (size_t)(kv0_) * 2 + vcb); \
        }                                                                    \
    }
#define SSTORE(bi_)                                                          \
    {                                                                        \
        _Pragma("unroll")                                                    \
        for (int it = 0; it < 4; ++it) {                                     \
            const int o = tid * 16 + it * 4096;                              \
            const int kr = o >> 8, kcb = o & 0xF0;                           \
            *(bf16x8*)((char*)Ks[bi_] + kr * 256 + (kcb ^ ((kr & 7) << 4))) = kst[it]; \
            const int vr = o >> 7, vcb = o & 0x70;                           \
            *(bf16x8*)((char*)Vs[bi_] + vr * 128 + (vcb ^ ((vr & 7) << 4))) = vst[it]; \
        }                                                                    \
    }

    GLOAD(kv_base);
    SSTORE(0);
    __syncthreads();

    f32x16 oacc[4];
#pragma unroll
    for (int i = 0; i < 4; ++i)
#pragma unroll
        for (int r = 0; r < 16; ++r) oacc[i][r] = 0.f;
    float m_r = -1e30f;
    float l_r = 0.f;

#pragma unroll 1
    for (int t = 0; t < NT; ++t) {
        const int bi = t & 1;
        if (t + 1 < NT) GLOAD(kv_base + 64 * (t + 1));

        const int kv0 = kv_base + 64 * t;
        if (kv0 <= q0w + 31) {
            f32x16 s0, s1;
#pragma unroll
            for (int r = 0; r < 16; ++r) { s0[r] = 0.f; s1[r] = 0.f; }
            __builtin_amdgcn_s_setprio(1);
#pragma unroll
            for (int ks = 0; ks < 8; ++ks) {
                const int col = ks * 32 + hi * 16;
                const int off0 = c5 * 256 + (col ^ ((c5 & 7) << 4));
                const int off1 = (32 + c5) * 256 + (col ^ ((c5 & 7) << 4));
                bf16x8 a0 = *(const bf16x8*)((char*)Ks[bi] + off0);
                bf16x8 a1 = *(const bf16x8*)((char*)Ks[bi] + off1);
                s0 = __builtin_amdgcn_mfma_f32_32x32x16_bf16(a0, qf[ks], s0, 0, 0, 0);
                s1 = __builtin_amdgcn_mfma_f32_32x32x16_bf16(a1, qf[ks], s1, 0, 0, 0);
            }
            __builtin_amdgcn_s_setprio(0);

            if (kv0 + 63 > q0w) {
#pragma unroll
                for (int r = 0; r < 16; ++r) {
                    const int key0 = kv0 + (r & 3) + 8 * (r >> 2) + 4 * hi;
                    if (key0 > qg)      s0[r] = -INFINITY;
                    if (key0 + 32 > qg) s1[r] = -INFINITY;
                }
            }

            float t8[8];
#pragma unroll
            for (int i = 0; i < 8; ++i)
                t8[i] = fmaxf(fmaxf(s0[2*i], s0[2*i+1]), fmaxf(s1[2*i], s1[2*i+1]));
            float smax = fmaxf(fmaxf(fmaxf(t8[0], t8[1]), fmaxf(t8[2], t8[3])),
                               fmaxf(fmaxf(t8[4], t8[5]), fmaxf(t8[6], t8[7])));
            smax = fmaxf(smax, __shfl_xor(smax, 32));

            const bool defer = __all(smax - m_r <= 8.0f);   // T13
            const float mnew = defer ? m_r : fmaxf(m_r, smax);
            if (!defer) {
                const float alpha = __expf(m_r - mnew);
                l_r *= alpha;
#pragma unroll
                for (int hb = 0; hb < 4; ++hb) oacc[hb] = oacc[hb] * alpha;
            }
            m_r = mnew;

#pragma unroll
            for (int r = 0; r < 16; ++r) {
                s0[r] = __expf(s0[r] - mnew);
                s1[r] = __expf(s1[r] - mnew);
            }
            float a8[8];
#pragma unroll
            for (int i = 0; i < 8; ++i)
                a8[i] = (s0[2*i] + s0[2*i+1]) + (s1[2*i] + s1[2*i+1]);
            float psum = ((a8[0] + a8[1]) + (a8[2] + a8[3])) +
                         ((a8[4] + a8[5]) + (a8[6] + a8[7]));
            psum += __shfl_xor(psum, 32);
            l_r += psum;

            bf16x8 pa[4];
#pragma unroll
            for (int kb2 = 0; kb2 < 2; ++kb2) {
#pragma unroll
                for (int par = 0; par < 2; ++par) {
                    const int e = par * 8;
                    float v0, v1, v2, v3, v4, v5, v6, v7;
                    if (kb2 == 0) {
                        v0=s0[e+0]; v1=s0[e+1]; v2=s0[e+2]; v3=s0[e+3];
                        v4=s0[e+4]; v5=s0[e+5]; v6=s0[e+6]; v7=s0[e+7];
                    } else {
                        v0=s1[e+0]; v1=s1[e+1]; v2=s1[e+2]; v3=s1[e+3];
                        v4=s1[e+4]; v5=s1[e+5]; v6=s1[e+6]; v7=s1[e+7];
                    }
                    const unsigned w0 = pkbf(v0, v1), w1 = pkbf(v2, v3);
                    const unsigned w2 = pkbf(v4, v5), w3 = pkbf(v6, v7);
                    const unsigned X0 = hi ? w0 : w2;
                    const unsigned X1 = hi ? w1 : w3;
                    const unsigned R0 = (unsigned)__shfl_xor((int)X0, 32);
                    const unsigned R1 = (unsigned)__shfl_xor((int)X1, 32);
                    union { unsigned w[4]; bf16x8 v; } uu;
                    uu.w[0] = hi ? R0 : w0;  uu.w[1] = hi ? R1 : w1;
                    uu.w[2] = hi ? w2 : R0;  uu.w[3] = hi ? w3 : R1;
                    pa[kb2 * 2 + par] = uu.v;
                }
            }

            __builtin_amdgcn_s_setprio(1);
#pragma unroll
            for (int hb = 0; hb < 4; ++hb) {
                const int row = hb * 32 + c5;
#pragma unroll
                for (int ks = 0; ks < 4; ++ks) {
                    const int off = row * 128 + ((ks * 32 + hi * 16) ^ ((row & 7) << 4));
                    bf16x8 va = *(const bf16x8*)((char*)Vs[bi] + off);
                    oacc[hb] = __builtin_amdgcn_mfma_f32_32x32x16_bf16(va, pa[ks], oacc[hb], 0, 0, 0);
                }
            }
            __builtin_amdgcn_s_setprio(0);
        }

        if (t + 1 < NT) {
            SSTORE(bi ^ 1);
            __syncthreads();
        }
    }

    // ---- epilogue: transpose O via LDS, store partials bf16 ----
    __syncthreads();
    char* sl = (char*)Ks + wid * 8192;
#pragma unroll
    for (int hb = 0; hb < 4; ++hb)
#pragma unroll
        for (int rq = 0; rq < 4; ++rq) {
            u16x4 o4;
            o4[0] = f2bf(oacc[hb][rq * 4 + 0]);
            o4[1] = f2bf(oacc[hb][rq * 4 + 1]);
            o4[2] = f2bf(oacc[hb][rq * 4 + 2]);
            o4[3] = f2bf(oacc[hb][rq * 4 + 3]);
            const int off = c5 * 256 + ((hb * 64 + rq * 16 + hi * 8) ^ ((c5 & 7) << 4));
            *(u16x4*)(sl + off) = o4;
        }
    asm volatile("s_waitcnt lgkmcnt(0)" ::: "memory");
    __builtin_amdgcn_sched_barrier(0);

    const int qr = lane >> 1, hf = lane & 1;
    unsigned short* Og = Opart + (size_t)pidx * 128 * 128 +
                         (size_t)(wid * 32 + qr) * 128 + hf * 64;
#pragma unroll
    for (int i = 0; i < 8; ++i) {
        const int off = qr * 256 + ((hf * 128 + i * 16) ^ ((qr & 7) << 4));
        *(u16x8*)(Og + i * 8) = *(const u16x8*)(sl + off);
    }
    if (hi == 0) {
        mpart[(size_t)pidx * 128 + wid * 32 + c5] = m_r;
        lpart[(size_t)pidx * 128 + wid * 32 + c5] = l_r;
    }
#undef GLOAD
#undef SSTORE
}

// ---------------------------------------------------------------------------
// Kernel 2b: combine partials (unchanged).
// ---------------------------------------------------------------------------
__global__ __launch_bounds__(256) void attn_combine(
    const unsigned short* __restrict__ Opart, const float* __restrict__ mpart,
    const float* __restrict__ lpart, float* __restrict__ out)
{
    const int qc = blockIdx.x;
    const int b  = blockIdx.y;
    const int n  = (qc >> 1) + 1;
    const int base = b * 72 + part_offs(qc);
    const int t   = threadIdx.x;
    const int row = t >> 1;
    const int d0  = (t & 1) * 64;

    float M = -INFINITY;
    for (int p = 0; p < n; ++p)
        M = fmaxf(M, mpart[(size_t)(base + p) * 128 + row]);
    float L = 0.f;
    for (int p = 0; p < n; ++p)
        L += __expf(mpart[(size_t)(base + p) * 128 + row] - M) *
             lpart[(size_t)(base + p) * 128 + row];

    float acc[64];
#pragma unroll
    for (int i = 0; i < 64; ++i) acc[i] = 0.f;

    for (int p = 0; p < n; ++p) {
        const float w = __expf(mpart[(size_t)(base + p) * 128 + row] - M);
        const bf16x8* src = (const bf16x8*)(Opart +
            ((size_t)(base + p) * 128 + row) * 128 + d0);
#pragma unroll
        for (int j = 0; j < 8; ++j) {
            bf16x8 v = src[j];
#pragma unroll
            for (int e = 0; e < 8; ++e) {
                union { unsigned u; float f; } x;
                x.u = ((unsigned)(unsigned short)v[e]) << 16;
                acc[j * 8 + e] += w * x.f;
            }
        }
    }

    const float invL = 1.f / L;
    float4* dst = (float4*)(out + ((size_t)(b * TLEN + qc * 128 + row)) * 128 + d0);
#pragma unroll
    for (int i = 0; i < 16; ++i)
        dst[i] = make_float4(acc[4*i] * invL, acc[4*i+1] * invL,
                             acc[4*i+2] * invL, acc[4*i+3] * invL);
}

extern "C" void kernel_launch(void* const* d_in, const int* in_sizes, int n_in,
                              void* d_out, int out_size, void* d_ws, size_t ws_size,
                              hipStream_t stream)
{
    const float* x  = (const float*)d_in[0];
    const float* Wq = (const float*)d_in[1];
    const float* Wk = (const float*)d_in[2];
    const float* Wv = (const float*)d_in[3];
    float* outp = (float*)d_out;

    const size_t per = (size_t)BATCH * TLEN * HDIM;      // 4,194,304
    unsigned short* qb  = (unsigned short*)d_ws;
    unsigned short* kb  = qb + per;
    unsigned short* vtb = kb + per;
    unsigned short* wtb = vtb + per;                     // 384*1024 bf16
    unsigned short* Opart = wtb + 384 * 1024;            // 1152*128*128 bf16
    float* mpart = (float*)(Opart + (size_t)1152 * 128 * 128);
    float* lpart = mpart + (size_t)1152 * 128;

    dim3 gw(512, 3);
    pack_w<<<gw, 256, 0, stream>>>(Wq, Wk, Wv, wtb);

    qkv_fused<<<512, 256, 0, stream>>>(x, wtb, qb, kb, vtb);

    dim3 g2(8, 16, BATCH);
    attn_partial<<<g2, 256, 0, stream>>>((const short*)qb, (const short*)kb,
                                         (const short*)vtb, Opart, mpart, lpart);

    dim3 g3(16, BATCH);
    attn_combine<<<g3, 256, 0, stream>>>(Opart, mpart, lpart, outp);
}

// Round 10
// 133.858 us; speedup vs baseline: 1.2299x; 1.0129x over previous
//
#include <hip/hip_runtime.h>
#include <hip/hip_bf16.h>

#define BATCH 16
#define TLEN 2048
#define CDIM 1024
#define HDIM 128

typedef __attribute__((ext_vector_type(8))) short bf16x8;
typedef __attribute__((ext_vector_type(4))) float f32x4;
typedef __attribute__((ext_vector_type(16))) float f32x16;
typedef __attribute__((ext_vector_type(4))) unsigned short u16x4;
typedef __attribute__((ext_vector_type(8))) unsigned short u16x8;

static __device__ __forceinline__ unsigned short f2bf(float f) {
    __hip_bfloat16 h = __float2bfloat16(f);
    return *(unsigned short*)&h;
}
static __device__ __forceinline__ unsigned pkbf(float a, float b) {
    return (unsigned)f2bf(a) | ((unsigned)f2bf(b) << 16);
}
// partials per (b,qc) prefix:  sum_{j<qc} (j/2 + 1)
static __device__ __forceinline__ int part_offs(int qc) {
    return qc + ((qc * qc - 2 * qc + (qc & 1)) >> 2);
}

typedef const __attribute__((address_space(1))) unsigned int* gas_t;
typedef __attribute__((address_space(3))) unsigned int* las_t;
static __device__ __forceinline__ void gl_lds16(const void* g, void* l) {
    __builtin_amdgcn_global_load_lds((gas_t)g, (las_t)l, 16, 0, 0);
}

// ---------------------------------------------------------------------------
// Prep: pack Wq|Wk|Wv into transposed bf16  wtb[(which*128+n)*1024 + k].
// ---------------------------------------------------------------------------
__global__ __launch_bounds__(256) void pack_w(
    const float* __restrict__ Wq, const float* __restrict__ Wk,
    const float* __restrict__ Wv, unsigned short* __restrict__ wtb)
{
    const int which = blockIdx.y;
    const float* W = (which == 0) ? Wq : (which == 1) ? Wk : Wv;
    const int n = blockIdx.x >> 2;
    const int k = (blockIdx.x & 3) * 256 + threadIdx.x;
    wtb[((size_t)which * 128 + n) * 1024 + k] = f2bf(W[(size_t)k * 128 + n]);
}

// ---------------------------------------------------------------------------
// Kernel 1: FUSED QKV projection.  C[64 x 384] per block, x read ONCE.
// BM=64, BN=384 (q|k|v), BK=32, 512 blocks (2/CU), 4 waves of 64x96.
// BOTH operands staged via global_load_lds w16 (A kept fp32 in LDS, converted
// to bf16 on the read side).  LDS linear-write + pre-swizzled global source +
// XOR-swizzled reads (rule-21 involution) -> conflict-free ds_read_b128.
// Double-buffered, STAGE issued before compute, ONE __syncthreads per K-step.
// ---------------------------------------------------------------------------
__global__ __launch_bounds__(256, 2) void qkv_fused(
    const float* __restrict__ x, const unsigned short* __restrict__ wtb,
    unsigned short* __restrict__ qb, unsigned short* __restrict__ kb,
    unsigned short* __restrict__ vtb)
{
    __shared__ __align__(16) float          Axf[2][64 * 32];    // 2 x 8KB  [m][k] f32, swizzled
    __shared__ __align__(16) unsigned short Bs[2][384 * 32];    // 2 x 24KB [n][k] bf16, swizzled

    const int tid  = threadIdx.x;
    const int lane = tid & 63, wid = tid >> 6;    // 4 waves
    const int c = lane & 15, g = lane >> 4;
    const int m0 = blockIdx.x * 64;

    f32x4 acc[4][6];
#pragma unroll
    for (int i = 0; i < 4; ++i)
#pragma unroll
        for (int j = 0; j < 6; ++j) acc[i][j] = (f32x4){0.f, 0.f, 0.f, 0.f};

    // A: 8 segs of 1024B (8 rows x 128B); wave owns segs {2w, 2w+1}.
    //    LDS linear: lane l -> row seg*8 + (l>>3), granule l&7 (16B = 4 f32).
    //    source granule = (l&7) ^ (row&7)   (involution)
    // B: 24 segs of 1024B (16 rows x 64B); wave owns segs w*6..w*6+5.
    //    lane l -> row seg*16 + (l>>2), granule l&3 (16B = 8 bf16).
    //    source granule = (l&3) ^ ((row>>1)&3)
#define STAGE(k0_, bi_)                                                      \
    { _Pragma("unroll")                                                      \
      for (int i_ = 0; i_ < 2; ++i_) {                                       \
          const int seg_ = wid * 2 + i_;                                     \
          const int row_ = seg_ * 8 + (lane >> 3);                           \
          const int col_ = (((lane & 7) ^ (row_ & 7)) << 2);                 \
          gl_lds16(x + (size_t)(m0 + row_) * CDIM + (k0_) + col_,            \
                   (char*)Axf[bi_] + seg_ * 1024);                           \
      }                                                                      \
      _Pragma("unroll")                                                      \
      for (int i_ = 0; i_ < 6; ++i_) {                                       \
          const int seg_ = wid * 6 + i_;                                     \
          const int row_ = seg_ * 16 + (lane >> 2);                          \
          const int col_ = (((lane & 3) ^ ((row_ >> 1) & 3)) << 3);          \
          gl_lds16(wtb + (size_t)row_ * 1024 + (k0_) + col_,                 \
                   (char*)Bs[bi_] + seg_ * 1024);                            \
      } }

    STAGE(0, 0);
    __syncthreads();

#pragma unroll 1
    for (int kt = 0; kt < 32; ++kt) {
        const int bi = kt & 1;
        if (kt < 31) STAGE((kt + 1) * 32, bi ^ 1);   // issue BEFORE compute

        // ---- fragments from LDS (swizzled reads) ----
        bf16x8 af[4], bf[6];
#pragma unroll
        for (int mf = 0; mf < 4; ++mf) {
            const int rm = mf * 16 + c;
            const char* base = (const char*)Axf[bi] + rm * 128;
            f32x4 lo = *(const f32x4*)(base + ((((2 * g)     ^ (rm & 7)) << 4)));
            f32x4 hi = *(const f32x4*)(base + ((((2 * g + 1) ^ (rm & 7)) << 4)));
            bf16x8 t;
            t[0] = f2bf(lo[0]); t[1] = f2bf(lo[1]); t[2] = f2bf(lo[2]); t[3] = f2bf(lo[3]);
            t[4] = f2bf(hi[0]); t[5] = f2bf(hi[1]); t[6] = f2bf(hi[2]); t[7] = f2bf(hi[3]);
            af[mf] = t;
        }
#pragma unroll
        for (int nf = 0; nf < 6; ++nf) {
            const int rn = wid * 96 + nf * 16 + c;
            bf[nf] = *(const bf16x8*)((const char*)Bs[bi] + rn * 64 +
                                      ((g ^ ((rn >> 1) & 3)) << 4));
        }

#pragma unroll
        for (int mf = 0; mf < 4; ++mf)
#pragma unroll
            for (int nf = 0; nf < 6; ++nf)
                acc[mf][nf] = __builtin_amdgcn_mfma_f32_16x16x32_bf16(
                    af[mf], bf[nf], acc[mf][nf], 0, 0, 0);

        __syncthreads();   // drains this step's gl_lds; next iter flips buffers
    }

    // ---- epilogue: per-fragment route to q (scaled) / k / v^T ----
#pragma unroll
    for (int mf = 0; mf < 4; ++mf) {
#pragma unroll
        for (int nf = 0; nf < 6; ++nf) {
            const int col0 = wid * 96 + nf * 16;
            const int nt = col0 >> 7;
            const int nc = (col0 & 127) + c;
            const int m = m0 + mf * 16 + g * 4;
            if (nt == 0) {
#pragma unroll
                for (int r = 0; r < 4; ++r)
                    qb[(size_t)(m + r) * HDIM + nc] = f2bf(acc[mf][nf][r] * 0.03125f);
            } else if (nt == 1) {
#pragma unroll
                for (int r = 0; r < 4; ++r)
                    kb[(size_t)(m + r) * HDIM + nc] = f2bf(acc[mf][nf][r]);
            } else {
                const int b = m >> 11, tl = m & (TLEN - 1);
                u16x4 o;
                o[0] = f2bf(acc[mf][nf][0]); o[1] = f2bf(acc[mf][nf][1]);
                o[2] = f2bf(acc[mf][nf][2]); o[3] = f2bf(acc[mf][nf][3]);
                *(u16x4*)(vtb + ((size_t)b * HDIM + nc) * TLEN + tl) = o;
            }
        }
    }
#undef STAGE
}

// ---------------------------------------------------------------------------
// Kernel 2a: flash-attention partials, 32x32 swapped-operand structure
// (unchanged from round 9 — passed).
// ---------------------------------------------------------------------------
__global__ __launch_bounds__(256, 2) void attn_partial(
    const short* __restrict__ qb, const short* __restrict__ kb,
    const short* __restrict__ vtb,
    unsigned short* __restrict__ Opart, float* __restrict__ mpart,
    float* __restrict__ lpart)
{
    const int kc = blockIdx.x;
    const int qc = blockIdx.y;
    const int b  = blockIdx.z;
    if (kc > (qc >> 1)) return;
    const int kv_base = kc * 256;
    const int qrel = qc * 128 - kv_base;
    int NT = ((qrel + 127) >> 6) + 1; if (NT > 4) NT = 4;

    __shared__ unsigned short Ks[2][64 * 128];
    __shared__ unsigned short Vs[2][128 * 64];

    const int tid  = threadIdx.x;
    const int wid  = tid >> 6;
    const int lane = tid & 63;
    const int c5 = lane & 31, hi = lane >> 5;
    const int q0w = qc * 128 + wid * 32;
    const int qg  = q0w + c5;
    const int pidx = b * 72 + part_offs(qc) + kc;

    const short* Kb  = kb  + (size_t)b * TLEN * HDIM;
    const short* Vtb = vtb + (size_t)b * HDIM * TLEN;

    bf16x8 qf[8];
#pragma unroll
    for (int ks = 0; ks < 8; ++ks)
        qf[ks] = *(const bf16x8*)(qb + ((size_t)b * TLEN + qg) * HDIM + ks * 16 + hi * 8);

    bf16x8 kst[4], vst[4];

#define GLOAD(kv0_)                                                          \
    {                                                                        \
        _Pragma("unroll")                                                    \
        for (int it = 0; it < 4; ++it) {                                     \
            const int o = tid * 16 + it * 4096;                              \
            const int kr = o >> 8, kcb = o & 0xF0;                           \
            kst[it] = *(const bf16x8*)((const char*)Kb +                     \
                        (size_t)((kv0_) + kr) * 256 + kcb);                  \
            const int vr = o >> 7, vcb = o & 0x70;                           \
            vst[it] = *(const bf16x8*)((const char*)Vtb +                    \
                        (size_t)vr * (TLEN * 2) + (size_t)(kv0_) * 2 + vcb); \
        }                                                                    \
    }
#define SSTORE(bi_)                                                          \
    {                                                                        \
        _Pragma("unroll")                                                    \
        for (int it = 0; it < 4; ++it) {                                     \
            const int o = tid * 16 + it * 4096;                              \
            const int kr = o >> 8, kcb = o & 0xF0;                           \
            *(bf16x8*)((char*)Ks[bi_] + kr * 256 + (kcb ^ ((kr & 7) << 4))) = kst[it]; \
            const int vr = o >> 7, vcb = o & 0x70;                           \
            *(bf16x8*)((char*)Vs[bi_] + vr * 128 + (vcb ^ ((vr & 7) << 4))) = vst[it]; \
        }                                                                    \
    }

    GLOAD(kv_base);
    SSTORE(0);
    __syncthreads();

    f32x16 oacc[4];
#pragma unroll
    for (int i = 0; i < 4; ++i)
#pragma unroll
        for (int r = 0; r < 16; ++r) oacc[i][r] = 0.f;
    float m_r = -1e30f;
    float l_r = 0.f;

#pragma unroll 1
    for (int t = 0; t < NT; ++t) {
        const int bi = t & 1;
        if (t + 1 < NT) GLOAD(kv_base + 64 * (t + 1));

        const int kv0 = kv_base + 64 * t;
        if (kv0 <= q0w + 31) {
            f32x16 s0, s1;
#pragma unroll
            for (int r = 0; r < 16; ++r) { s0[r] = 0.f; s1[r] = 0.f; }
            __builtin_amdgcn_s_setprio(1);
#pragma unroll
            for (int ks = 0; ks < 8; ++ks) {
                const int col = ks * 32 + hi * 16;
                const int off0 = c5 * 256 + (col ^ ((c5 & 7) << 4));
                const int off1 = (32 + c5) * 256 + (col ^ ((c5 & 7) << 4));
                bf16x8 a0 = *(const bf16x8*)((char*)Ks[bi] + off0);
                bf16x8 a1 = *(const bf16x8*)((char*)Ks[bi] + off1);
                s0 = __builtin_amdgcn_mfma_f32_32x32x16_bf16(a0, qf[ks], s0, 0, 0, 0);
                s1 = __builtin_amdgcn_mfma_f32_32x32x16_bf16(a1, qf[ks], s1, 0, 0, 0);
            }
            __builtin_amdgcn_s_setprio(0);

            if (kv0 + 63 > q0w) {
#pragma unroll
                for (int r = 0; r < 16; ++r) {
                    const int key0 = kv0 + (r & 3) + 8 * (r >> 2) + 4 * hi;
                    if (key0 > qg)      s0[r] = -INFINITY;
                    if (key0 + 32 > qg) s1[r] = -INFINITY;
                }
            }

            float t8[8];
#pragma unroll
            for (int i = 0; i < 8; ++i)
                t8[i] = fmaxf(fmaxf(s0[2*i], s0[2*i+1]), fmaxf(s1[2*i], s1[2*i+1]));
            float smax = fmaxf(fmaxf(fmaxf(t8[0], t8[1]), fmaxf(t8[2], t8[3])),
                               fmaxf(fmaxf(t8[4], t8[5]), fmaxf(t8[6], t8[7])));
            smax = fmaxf(smax, __shfl_xor(smax, 32));

            const bool defer = __all(smax - m_r <= 8.0f);   // T13
            const float mnew = defer ? m_r : fmaxf(m_r, smax);
            if (!defer) {
                const float alpha = __expf(m_r - mnew);
                l_r *= alpha;
#pragma unroll
                for (int hb = 0; hb < 4; ++hb) oacc[hb] = oacc[hb] * alpha;
            }
            m_r = mnew;

#pragma unroll
            for (int r = 0; r < 16; ++r) {
                s0[r] = __expf(s0[r] - mnew);
                s1[r] = __expf(s1[r] - mnew);
            }
            float a8[8];
#pragma unroll
            for (int i = 0; i < 8; ++i)
                a8[i] = (s0[2*i] + s0[2*i+1]) + (s1[2*i] + s1[2*i+1]);
            float psum = ((a8[0] + a8[1]) + (a8[2] + a8[3])) +
                         ((a8[4] + a8[5]) + (a8[6] + a8[7]));
            psum += __shfl_xor(psum, 32);
            l_r += psum;

            bf16x8 pa[4];
#pragma unroll
            for (int kb2 = 0; kb2 < 2; ++kb2) {
#pragma unroll
                for (int par = 0; par < 2; ++par) {
                    const int e = par * 8;
                    float v0, v1, v2, v3, v4, v5, v6, v7;
                    if (kb2 == 0) {
                        v0=s0[e+0]; v1=s0[e+1]; v2=s0[e+2]; v3=s0[e+3];
                        v4=s0[e+4]; v5=s0[e+5]; v6=s0[e+6]; v7=s0[e+7];
                    } else {
                        v0=s1[e+0]; v1=s1[e+1]; v2=s1[e+2]; v3=s1[e+3];
                        v4=s1[e+4]; v5=s1[e+5]; v6=s1[e+6]; v7=s1[e+7];
                    }
                    const unsigned w0 = pkbf(v0, v1), w1 = pkbf(v2, v3);
                    const unsigned w2 = pkbf(v4, v5), w3 = pkbf(v6, v7);
                    const unsigned X0 = hi ? w0 : w2;
                    const unsigned X1 = hi ? w1 : w3;
                    const unsigned R0 = (unsigned)__shfl_xor((int)X0, 32);
                    const unsigned R1 = (unsigned)__shfl_xor((int)X1, 32);
                    union { unsigned w[4]; bf16x8 v; } uu;
                    uu.w[0] = hi ? R0 : w0;  uu.w[1] = hi ? R1 : w1;
                    uu.w[2] = hi ? w2 : R0;  uu.w[3] = hi ? w3 : R1;
                    pa[kb2 * 2 + par] = uu.v;
                }
            }

            __builtin_amdgcn_s_setprio(1);
#pragma unroll
            for (int hb = 0; hb < 4; ++hb) {
                const int row = hb * 32 + c5;
#pragma unroll
                for (int ks = 0; ks < 4; ++ks) {
                    const int off = row * 128 + ((ks * 32 + hi * 16) ^ ((row & 7) << 4));
                    bf16x8 va = *(const bf16x8*)((char*)Vs[bi] + off);
                    oacc[hb] = __builtin_amdgcn_mfma_f32_32x32x16_bf16(va, pa[ks], oacc[hb], 0, 0, 0);
                }
            }
            __builtin_amdgcn_s_setprio(0);
        }

        if (t + 1 < NT) {
            SSTORE(bi ^ 1);
            __syncthreads();
        }
    }

    // ---- epilogue: transpose O via LDS, store partials bf16 ----
    __syncthreads();
    char* sl = (char*)Ks + wid * 8192;
#pragma unroll
    for (int hb = 0; hb < 4; ++hb)
#pragma unroll
        for (int rq = 0; rq < 4; ++rq) {
            u16x4 o4;
            o4[0] = f2bf(oacc[hb][rq * 4 + 0]);
            o4[1] = f2bf(oacc[hb][rq * 4 + 1]);
            o4[2] = f2bf(oacc[hb][rq * 4 + 2]);
            o4[3] = f2bf(oacc[hb][rq * 4 + 3]);
            const int off = c5 * 256 + ((hb * 64 + rq * 16 + hi * 8) ^ ((c5 & 7) << 4));
            *(u16x4*)(sl + off) = o4;
        }
    asm volatile("s_waitcnt lgkmcnt(0)" ::: "memory");
    __builtin_amdgcn_sched_barrier(0);

    const int qr = lane >> 1, hf = lane & 1;
    unsigned short* Og = Opart + (size_t)pidx * 128 * 128 +
                         (size_t)(wid * 32 + qr) * 128 + hf * 64;
#pragma unroll
    for (int i = 0; i < 8; ++i) {
        const int off = qr * 256 + ((hf * 128 + i * 16) ^ ((qr & 7) << 4));
        *(u16x8*)(Og + i * 8) = *(const u16x8*)(sl + off);
    }
    if (hi == 0) {
        mpart[(size_t)pidx * 128 + wid * 32 + c5] = m_r;
        lpart[(size_t)pidx * 128 + wid * 32 + c5] = l_r;
    }
#undef GLOAD
#undef SSTORE
}

// ---------------------------------------------------------------------------
// Kernel 2b: combine partials (unchanged).
// ---------------------------------------------------------------------------
__global__ __launch_bounds__(256) void attn_combine(
    const unsigned short* __restrict__ Opart, const float* __restrict__ mpart,
    const float* __restrict__ lpart, float* __restrict__ out)
{
    const int qc = blockIdx.x;
    const int b  = blockIdx.y;
    const int n  = (qc >> 1) + 1;
    const int base = b * 72 + part_offs(qc);
    const int t   = threadIdx.x;
    const int row = t >> 1;
    const int d0  = (t & 1) * 64;

    float M = -INFINITY;
    for (int p = 0; p < n; ++p)
        M = fmaxf(M, mpart[(size_t)(base + p) * 128 + row]);
    float L = 0.f;
    for (int p = 0; p < n; ++p)
        L += __expf(mpart[(size_t)(base + p) * 128 + row] - M) *
             lpart[(size_t)(base + p) * 128 + row];

    float acc[64];
#pragma unroll
    for (int i = 0; i < 64; ++i) acc[i] = 0.f;

    for (int p = 0; p < n; ++p) {
        const float w = __expf(mpart[(size_t)(base + p) * 128 + row] - M);
        const bf16x8* src = (const bf16x8*)(Opart +
            ((size_t)(base + p) * 128 + row) * 128 + d0);
#pragma unroll
        for (int j = 0; j < 8; ++j) {
            bf16x8 v = src[j];
#pragma unroll
            for (int e = 0; e < 8; ++e) {
                union { unsigned u; float f; } x;
                x.u = ((unsigned)(unsigned short)v[e]) << 16;
                acc[j * 8 + e] += w * x.f;
            }
        }
    }

    const float invL = 1.f / L;
    float4* dst = (float4*)(out + ((size_t)(b * TLEN + qc * 128 + row)) * 128 + d0);
#pragma unroll
    for (int i = 0; i < 16; ++i)
        dst[i] = make_float4(acc[4*i] * invL, acc[4*i+1] * invL,
                             acc[4*i+2] * invL, acc[4*i+3] * invL);
}

extern "C" void kernel_launch(void* const* d_in, const int* in_sizes, int n_in,
                              void* d_out, int out_size, void* d_ws, size_t ws_size,
                              hipStream_t stream)
{
    const float* x  = (const float*)d_in[0];
    const float* Wq = (const float*)d_in[1];
    const float* Wk = (const float*)d_in[2];
    const float* Wv = (const float*)d_in[3];
    float* outp = (float*)d_out;

    const size_t per = (size_t)BATCH * TLEN * HDIM;      // 4,194,304
    unsigned short* qb  = (unsigned short*)d_ws;
    unsigned short* kb  = qb + per;
    unsigned short* vtb = kb + per;
    unsigned short* wtb = vtb + per;                     // 384*1024 bf16
    unsigned short* Opart = wtb + 384 * 1024;            // 1152*128*128 bf16
    float* mpart = (float*)(Opart + (size_t)1152 * 128 * 128);
    float* lpart = mpart + (size_t)1152 * 128;

    dim3 gw(512, 3);
    pack_w<<<gw, 256, 0, stream>>>(Wq, Wk, Wv, wtb);

    qkv_fused<<<512, 256, 0, stream>>>(x, wtb, qb, kb, vtb);

    dim3 g2(8, 16, BATCH);
    attn_partial<<<g2, 256, 0, stream>>>((const short*)qb, (const short*)kb,
                                         (const short*)vtb, Opart, mpart, lpart);

    dim3 g3(16, BATCH);
    attn_combine<<<g3, 256, 0, stream>>>(Opart, mpart, lpart, outp);
}